// Round 8
// baseline (190.496 us; speedup 1.0000x reference)
//
#include <hip/hip_runtime.h>
#include <math.h>

#define Bn 16
#define Cn 64
#define Tn 1024
#define Dn 1024

// ---- workspace layout (float element offsets) ----
#define CA_S   1088
#define CA_OFF 0                                 // [B][1088], end 17408
#define AT_OFF 17408                             // attn [B][1024], end 33792
#define A2_S   1026
#define A2_OFF 599040                            // fp32 a2 [B*64][1026], end 1649664
// XS overlays old float region (dead by the time k4b writes):
#define XS_U   (2*50176)                         // bf16 [4][B*C][1280]
#define HS_S   1040
#define HS_OFF 2671616                           // fp32 [2][B][64][1040], end 4801536
#define HB_OFF 4801536

// ---- ushort offsets ----
#define A1S_U  (2*HS_OFF)                        // bf16 a1 shifted [4][512][1216] (overlays HS; dead before k5)
#define HBT_U  (2*HB_OFF)                        // bf16 hbT [B][1024][64]
#define WFW2_U (HBT_U + 1048576)                 // bf16 fw2 [1024][64]
#define WAW2_U (WFW2_U + 65536)                  // bf16 aw2 [64][32][32]
#define WFW1_U (WAW2_U + 65536)                  // bf16 fw1 [64][128]

typedef __attribute__((ext_vector_type(4))) float f32x4;
typedef __attribute__((ext_vector_type(8))) short bf16x8;
typedef __attribute__((ext_vector_type(4))) unsigned int u32x4;

static __device__ inline unsigned short f2bf(float x) {
  unsigned u = __builtin_bit_cast(unsigned, x);
  return (unsigned short)((u + 0x7fffu + ((u >> 16) & 1u)) >> 16);
}

// KI: blocks 0..63: ca[b][t] = fs/64 * sum_c eeg (overwrite, incl. pads)
//     blocks 64..199: convert aw2 (16384 ids) / fw2 (16384) / fw1 (2048) -> bf16
__global__ void kI_init(const float* __restrict__ eeg, const float* __restrict__ fsp,
                        const float* __restrict__ aw2, const float* __restrict__ fw2,
                        const float* __restrict__ fw1, float* __restrict__ ws) {
  int bx = blockIdx.x, tid = threadIdx.x;
  if (bx < 64) {
    int b = bx >> 2, x = bx & 3;
    int t = x * 256 + tid;
    float s = 0.f;
#pragma unroll 8
    for (int c = 0; c < 64; ++c) s += eeg[(b * 64 + c) * 1024 + t];
    ws[CA_OFF + b * CA_S + 32 + t] = s * fsp[0] * (1.f / 64.f);
    if (x == 0 && tid < 32) ws[CA_OFF + b * CA_S + tid] = 0.f;
    if (x == 3 && tid >= 224) ws[CA_OFF + b * CA_S + 1056 + (tid - 224)] = 0.f;
    return;
  }
  int id = (bx - 64) * 256 + tid;
  if (id < 16384) {                       // aw2: 65536 elems
    int e0 = id * 4;
    float4 f = *(const float4*)&aw2[e0];
    unsigned short* d = (unsigned short*)ws + WAW2_U + e0;
    d[0] = f2bf(f.x); d[1] = f2bf(f.y); d[2] = f2bf(f.z); d[3] = f2bf(f.w);
  } else if (id < 32768) {                // fw2: 65536 elems
    int e0 = (id - 16384) * 4;
    float4 f = *(const float4*)&fw2[e0];
    unsigned short* d = (unsigned short*)ws + WFW2_U + e0;
    d[0] = f2bf(f.x); d[1] = f2bf(f.y); d[2] = f2bf(f.z); d[3] = f2bf(f.w);
  } else if (id < 34816) {                // fw1: 8192 elems
    int e0 = (id - 32768) * 4;
    float4 f = *(const float4*)&fw1[e0];
    unsigned short* d = (unsigned short*)ws + WFW1_U + e0;
    d[0] = f2bf(f.x); d[1] = f2bf(f.y); d[2] = f2bf(f.z); d[3] = f2bf(f.w);
  }
}

// K2s: per (b,o) row: a1 = relu(conv1d(ca, aw1, pad=32)) computed in LDS,
// then write 4 shifted bf16 copies directly. 512 blocks.
__global__ void k2s_conv1(const float* __restrict__ aw1, const float* __restrict__ ab1,
                          float* __restrict__ ws) {
  int row = blockIdx.x;            // b*32 + o
  int b = row >> 5, o = row & 31;
  int tid = threadIdx.x;
  __shared__ unsigned short xl[1232];
  for (int i = tid; i < 1232; i += 256)
    if (i < 16 || i >= 1041) xl[i] = 0;
  const float* cab = ws + CA_OFF + b * CA_S;
  float bias = ab1[o];
  for (int t = tid; t < 1025; t += 256) {
    float acc = bias;
#pragma unroll 8
    for (int k = 0; k < 64; ++k) acc += aw1[o * 64 + k] * cab[t + k];
    xl[16 + t] = f2bf(fmaxf(acc, 0.f));
  }
  __syncthreads();
  unsigned short* a1s = (unsigned short*)ws + A1S_U;
  for (int q = tid; q < 608; q += 256) {
    int s = q / 152, mm = q % 152;
    int e = mm * 8;
    unsigned a0 = xl[e + s + 0], a1 = xl[e + s + 1], a2 = xl[e + s + 2], a3 = xl[e + s + 3];
    unsigned a4 = xl[e + s + 4], a5 = xl[e + s + 5], a6 = xl[e + s + 6], a7 = xl[e + s + 7];
    uint4 v;
    v.x = a0 | (a1 << 16); v.y = a2 | (a3 << 16); v.z = a4 | (a5 << 16); v.w = a6 | (a7 << 16);
    *(uint4*)&a1s[(s * 512 + row) * 1216 + e] = v;
  }
}

// K3: MFMA conv2, weights direct from L2-hot bf16 aw2 (no weight LDS).
// LDS 26.6KB -> ~4 blocks/CU, grid 1088 ~ one residency round.
__global__ __launch_bounds__(256) void k3_mfma(const float* __restrict__ ab2,
                                               float* __restrict__ ws) {
  int t0 = blockIdx.x * 64, b = blockIdx.y, oh = blockIdx.z;
  int tid = threadIdx.x, l = tid & 63, w = tid >> 6;
  __shared__ unsigned short xlds[32 * 4 * 104];
  const unsigned short* wb = (const unsigned short*)ws + WAW2_U;
  const unsigned short* a1s = (const unsigned short*)ws + A1S_U;
#pragma unroll
  for (int r = 0; r < 6; ++r) {
    int idx = tid + r * 256;
    int i = idx / 48, rem = idx % 48, s = rem / 12, mm = rem % 12;
    *(uint4*)&xlds[(i * 4 + s) * 104 + mm * 8] =
        *(const uint4*)&a1s[(s * 512 + b * 32 + i) * 1216 + t0 + mm * 8];
  }
  __syncthreads();
  int m = l & 15, q = l >> 4;
  int A0 = w * 16 + m + q * 8;
  int xoffb = (A0 & 3) * 104 + (A0 & ~3);
  const unsigned short* wrow = wb + (oh * 16 + m) * 1024 + q * 8;  // [i*32 + ...]
  f32x4 acc = (f32x4){0.f, 0.f, 0.f, 0.f};
  for (int i = 0; i < 32; ++i) {
    const uint2* p = (const uint2*)&xlds[i * 416 + xoffb];
    uint2 lo = p[0], hi = p[1];
    u32x4 bb; bb.x = lo.x; bb.y = lo.y; bb.z = hi.x; bb.w = hi.y;
    u32x4 a = *(const u32x4*)&wrow[i * 32];
    acc = __builtin_amdgcn_mfma_f32_16x16x32_bf16(
        __builtin_bit_cast(bf16x8, a), __builtin_bit_cast(bf16x8, bb), acc, 0, 0, 0);
  }
  int t = t0 + w * 16 + m;
  if (t < 1026) {
#pragma unroll
    for (int r = 0; r < 4; ++r) {
      int o = oh * 16 + q * 4 + r;
      ws[A2_OFF + (b * 64 + o) * A2_S + t] = fmaxf(acc[r] + ab2[o], 0.f);
    }
  }
}

// K4: fused pooled 1x1 conv + sigmoid -> attn + out2. 64 blocks.
__global__ void k4_attn(const float* __restrict__ aw3, const float* __restrict__ ab3,
                        float* __restrict__ ws, float* __restrict__ out) {
  int b = blockIdx.y, t = blockIdx.x * 256 + threadIdx.x;
  int s = t + (t >= 512 ? 1 : 0);
  float acc = 0.f;
#pragma unroll 8
  for (int i = 0; i < 64; ++i) {
    const float* row = ws + A2_OFF + (b * 64 + i) * A2_S;
    acc += aw3[i] * (row[s] + row[s + 1]);
  }
  float a = 1.f / (1.f + expf(-(acc * 0.5f + ab3[0])));
  ws[AT_OFF + b * 1024 + t] = a;
  out[16777216 + b * 1024 + t] = a;
}

// K4b: build 4 shifted bf16 copies of xs_pad = pad64(eeg*fs*attn), row len 1280
__global__ void k4b_xs(const float* __restrict__ eeg, const float* __restrict__ fsp,
                       float* __restrict__ ws) {
  int bc = blockIdx.x;
  int b = bc >> 6;
  int tid = threadIdx.x;
  __shared__ unsigned short xsl[1288];
  float fs = fsp[0];
  for (int i = tid; i < 1288; i += 256) {
    int j = i - 64;
    float v = 0.f;
    if (j >= 0 && j < 1024) v = eeg[bc * 1024 + j] * fs * ws[AT_OFF + b * 1024 + j];
    xsl[i] = f2bf(v);
  }
  __syncthreads();
  unsigned short* xsg = (unsigned short*)ws + XS_U;
  for (int q = tid; q < 640; q += 256) {
    int s = q / 160, m = q % 160, e = m * 8;
    uint4 v;
    unsigned a0 = xsl[e + s + 0], a1 = xsl[e + s + 1], a2 = xsl[e + s + 2], a3 = xsl[e + s + 3];
    unsigned a4 = xsl[e + s + 4], a5 = xsl[e + s + 5], a6 = xsl[e + s + 6], a7 = xsl[e + s + 7];
    v.x = a0 | (a1 << 16); v.y = a2 | (a3 << 16); v.z = a4 | (a5 << 16); v.w = a6 | (a7 << 16);
    *(uint4*)&xsg[(s * 1024 + bc) * 1280 + e] = v;
  }
}

// K5: MFMA stage-B conv. Weight frags direct from global (L2-hot 16KB);
// LDS = xlds only (51.2KB) -> 3 blocks/CU.
__global__ __launch_bounds__(256, 3) void k5_mfma(
    const float* __restrict__ fb1,
    const float* __restrict__ bng, const float* __restrict__ bnb,
    const float* __restrict__ bnm, const float* __restrict__ bnv,
    float* __restrict__ ws) {
  int t0 = blockIdx.x * 64, b = blockIdx.y, g2 = blockIdx.z;
  int tid = threadIdx.x, l = tid & 63, w = tid >> 6;
  __shared__ unsigned short xlds[32 * 4 * 200];
  const unsigned short* wbf = (const unsigned short*)ws + WFW1_U;
  const unsigned short* xsg = (const unsigned short*)ws + XS_U;
#pragma unroll
  for (int r = 0; r < 12; ++r) {
    int q = tid + r * 256;
    int ch = q / 96, rem = q % 96, s = rem / 24, m = rem % 24;
    int c = g2 * 32 + ch;
    uint4 v = *(const uint4*)&xsg[((s * 1024) + b * 64 + c) * 1280 + t0 + m * 8];
    *(uint4*)&xlds[(ch * 4 + s) * 200 + m * 8] = v;
  }
  u32x4 wf[4][4];
#pragma unroll
  for (int mt = 0; mt < 4; ++mt)
#pragma unroll
    for (int ks = 0; ks < 4; ++ks)
      wf[mt][ks] = *(const u32x4*)&wbf[(mt * 16 + (l & 15)) * 128 + ks * 32 + (l >> 4) * 8];
  int row0 = (l >> 4) * 4;
  float scv[4][4], shv[4][4];
#pragma unroll
  for (int mt = 0; mt < 4; ++mt)
#pragma unroll
    for (int r = 0; r < 4; ++r) {
      int o = mt * 16 + row0 + r;
      float s = bng[o] * rsqrtf(bnv[o] + 1e-5f);
      scv[mt][r] = s;
      shv[mt][r] = (fb1[o] - bnm[o]) * s + bnb[o];
    }
  int xoff[4];
#pragma unroll
  for (int ks = 0; ks < 4; ++ks) {
    int A0 = (l & 15) + ks * 32 + (l >> 4) * 8;
    int s = A0 & 3, e = A0 & ~3;
    xoff[ks] = s * 200 + w * 16 + e;
  }
  __syncthreads();
  f32x4 acc[4];
#pragma unroll
  for (int mt = 0; mt < 4; ++mt) acc[mt] = (f32x4){0.f, 0.f, 0.f, 0.f};
  for (int ch = 0; ch < 32; ++ch) {
    u32x4 bf[4];
#pragma unroll
    for (int ks = 0; ks < 4; ++ks) {
      const uint2* p = (const uint2*)&xlds[ch * 800 + xoff[ks]];
      uint2 lo = p[0], hi = p[1];
      u32x4 bb; bb.x = lo.x; bb.y = lo.y; bb.z = hi.x; bb.w = hi.y;
      bf[ks] = bb;
    }
#pragma unroll
    for (int mt = 0; mt < 4; ++mt) {
      f32x4 c = (f32x4){0.f, 0.f, 0.f, 0.f};
#pragma unroll
      for (int ks = 0; ks < 4; ++ks)
        c = __builtin_amdgcn_mfma_f32_16x16x32_bf16(
            __builtin_bit_cast(bf16x8, wf[mt][ks]),
            __builtin_bit_cast(bf16x8, bf[ks]), c, 0, 0, 0);
#pragma unroll
      for (int r = 0; r < 4; ++r)
        acc[mt][r] += fmaxf(c[r] * scv[mt][r] + shv[mt][r], 0.f);
    }
  }
  int t = t0 + w * 16 + (l & 15);
  if (t < 1025) {
#pragma unroll
    for (int mt = 0; mt < 4; ++mt)
#pragma unroll
      for (int r = 0; r < 4; ++r)
        ws[HS_OFF + (((g2 * 16 + b) * 64) + mt * 16 + row0 + r) * HS_S + t] = acc[mt][r];
  }
}

// K5b: pool + channel-mean + transpose -> hbT[b][t][k] bf16
__global__ void k5b_t(float* __restrict__ ws) {
  int tt = blockIdx.x, b = blockIdx.y;
  int tid = threadIdx.x;
  __shared__ unsigned short tr[64 * 80];
  int k = tid >> 2, q = tid & 3;
  const float* r0 = ws + HS_OFF + ((0 + b) * 64 + k) * HS_S + tt * 64;
  const float* r1 = ws + HS_OFF + ((16 + b) * 64 + k) * HS_S + tt * 64;
#pragma unroll
  for (int j = 0; j < 16; ++j) {
    int tl = q * 16 + j;
    float v = r0[tl] + r0[tl + 1] + r1[tl] + r1[tl + 1];
    tr[tl * 80 + k] = f2bf(v * (1.f / 128.f));
  }
  __syncthreads();
  unsigned short* hbT = (unsigned short*)ws + HBT_U;
#pragma unroll
  for (int r = 0; r < 2; ++r) {
    int idx = tid + r * 256;
    int tl = idx >> 3, j = idx & 7;
    uint4 v = *(uint4*)&tr[tl * 80 + j * 8];
    *(uint4*)&hbT[(b * 1024 + tt * 64 + tl) * 64 + j * 8] = v;
  }
}

// K6: MFMA out-GEMM: out[b][d][t] = sum_k fw2[d][k]*hb[k][t] + fb2[d]
__global__ __launch_bounds__(256) void k6_mfma(const float* __restrict__ fb2,
                                               float* __restrict__ ws,
                                               float* __restrict__ out) {
  int tt = blockIdx.x, dt = blockIdx.y, b = blockIdx.z;
  int tid = threadIdx.x, l = tid & 63, w = tid >> 6;
  int wd = w >> 1, wt = w & 1;
  __shared__ unsigned short wA[64 * 80], xB[64 * 80];
  const unsigned short* w2 = (const unsigned short*)ws + WFW2_U;
  const unsigned short* hbT = (const unsigned short*)ws + HBT_U;
#pragma unroll
  for (int r = 0; r < 2; ++r) {
    int idx = tid + r * 256;
    int row = idx >> 3, j = idx & 7;
    *(uint4*)&wA[row * 80 + j * 8] = *(const uint4*)&w2[(dt * 64 + row) * 64 + j * 8];
    *(uint4*)&xB[row * 80 + j * 8] = *(const uint4*)&hbT[(b * 1024 + tt * 64 + row) * 64 + j * 8];
  }
  __syncthreads();
  int m = l & 15, q = l >> 4;
  f32x4 acc[2][2];
#pragma unroll
  for (int mt = 0; mt < 2; ++mt)
#pragma unroll
    for (int nt = 0; nt < 2; ++nt) acc[mt][nt] = (f32x4){0.f, 0.f, 0.f, 0.f};
#pragma unroll
  for (int ks = 0; ks < 2; ++ks) {
    u32x4 a[2], bb[2];
#pragma unroll
    for (int mt = 0; mt < 2; ++mt)
      a[mt] = *(const u32x4*)&wA[(wd * 32 + mt * 16 + m) * 80 + ks * 32 + q * 8];
#pragma unroll
    for (int nt = 0; nt < 2; ++nt)
      bb[nt] = *(const u32x4*)&xB[(wt * 32 + nt * 16 + m) * 80 + ks * 32 + q * 8];
#pragma unroll
    for (int mt = 0; mt < 2; ++mt)
#pragma unroll
      for (int nt = 0; nt < 2; ++nt)
        acc[mt][nt] = __builtin_amdgcn_mfma_f32_16x16x32_bf16(
            __builtin_bit_cast(bf16x8, a[mt]), __builtin_bit_cast(bf16x8, bb[nt]),
            acc[mt][nt], 0, 0, 0);
  }
#pragma unroll
  for (int mt = 0; mt < 2; ++mt) {
#pragma unroll
    for (int r = 0; r < 4; ++r) {
      int d = dt * 64 + wd * 32 + mt * 16 + q * 4 + r;
      float bias = fb2[d];
#pragma unroll
      for (int nt = 0; nt < 2; ++nt) {
        int t = tt * 64 + wt * 32 + nt * 16 + m;
        out[(b * 1024 + d) * 1024 + t] = acc[mt][nt][r] + bias;
      }
    }
  }
}

extern "C" void kernel_launch(void* const* d_in, const int* in_sizes, int n_in,
                              void* d_out, int out_size, void* d_ws, size_t ws_size,
                              hipStream_t stream) {
  const float* eeg = (const float*)d_in[0];
  const float* fsp = (const float*)d_in[1];
  const float* aw1 = (const float*)d_in[2];
  const float* ab1 = (const float*)d_in[3];
  const float* aw2 = (const float*)d_in[4];
  const float* ab2 = (const float*)d_in[5];
  const float* aw3 = (const float*)d_in[6];
  const float* ab3 = (const float*)d_in[7];
  const float* fw1 = (const float*)d_in[8];
  const float* fb1 = (const float*)d_in[9];
  const float* bng = (const float*)d_in[10];
  const float* bnb = (const float*)d_in[11];
  const float* bnm = (const float*)d_in[12];
  const float* bnv = (const float*)d_in[13];
  const float* fw2 = (const float*)d_in[14];
  const float* fb2 = (const float*)d_in[15];
  float* out = (float*)d_out;
  float* ws = (float*)d_ws;

  hipLaunchKernelGGL(kI_init, dim3(200), dim3(256), 0, stream, eeg, fsp, aw2, fw2, fw1, ws);
  hipLaunchKernelGGL(k2s_conv1, dim3(512), dim3(256), 0, stream, aw1, ab1, ws);
  hipLaunchKernelGGL(k3_mfma, dim3(17, 16, 4), dim3(256), 0, stream, ab2, ws);
  hipLaunchKernelGGL(k4_attn, dim3(4, 16), dim3(256), 0, stream, aw3, ab3, ws, out);
  hipLaunchKernelGGL(k4b_xs, dim3(1024), dim3(256), 0, stream, eeg, fsp, ws);
  hipLaunchKernelGGL(k5_mfma, dim3(17, 16, 2), dim3(256), 0, stream,
                     fb1, bng, bnb, bnm, bnv, ws);
  hipLaunchKernelGGL(k5b_t, dim3(16, 16), dim3(256), 0, stream, ws);
  hipLaunchKernelGGL(k6_mfma, dim3(16, 16, 16), dim3(256), 0, stream, fb2, ws, out);
}

// Round 9
// 181.214 us; speedup vs baseline: 1.0512x; 1.0512x over previous
//
#include <hip/hip_runtime.h>
#include <math.h>

#define Bn 16
#define Cn 64
#define Tn 1024
#define Dn 1024

// ---- workspace layout (float element offsets) ----
#define CA_S   1088
#define CA_OFF 0                                 // [B][1088], end 17408
#define AT_OFF 17408                             // attn [B][1024], end 33792
#define A2_S   1026
#define A2_OFF 599040                            // fp32 a2 [B*64][1026], end 1649664
#define HS_OFF 2671616                           // (legacy anchor for ushort offsets)
#define HB_OFF 4801536

// ---- ushort offsets ----
#define XS_U   (2*50176)                         // bf16 xs [4][B*C][1280], ends 5343232
#define A1S_U  (2*HS_OFF)                        // bf16 a1 shifted [4][512][1216] (5343232..7833600; dead after k3)
#define HSB_U  A1S_U                             // bf16 Hsum/128 [2][B][64][1040] (5343232..7473152; overlays A1S)
#define HBT_U  (2*HB_OFF)                        // (unused)
#define WFW2_U (HBT_U + 1048576)                 // bf16 fw2 [1024][64]
#define WAW2_U (WFW2_U + 65536)                  // bf16 aw2 [64][32][32]
#define WFW1_U (WAW2_U + 65536)                  // bf16 fw1 [64][128]

typedef __attribute__((ext_vector_type(4))) float f32x4;
typedef __attribute__((ext_vector_type(8))) short bf16x8;
typedef __attribute__((ext_vector_type(4))) unsigned int u32x4;

static __device__ inline unsigned short f2bf(float x) {
  unsigned u = __builtin_bit_cast(unsigned, x);
  return (unsigned short)((u + 0x7fffu + ((u >> 16) & 1u)) >> 16);
}
static __device__ inline float bf2f(unsigned short h) {
  unsigned u = ((unsigned)h) << 16;
  return __builtin_bit_cast(float, u);
}

// KI: blocks 0..63: ca[b][t] = fs/64 * sum_c eeg (overwrite, incl. pads)
//     blocks 64..199: convert aw2 (16384 ids) / fw2 (16384) / fw1 (2048) -> bf16
__global__ void kI_init(const float* __restrict__ eeg, const float* __restrict__ fsp,
                        const float* __restrict__ aw2, const float* __restrict__ fw2,
                        const float* __restrict__ fw1, float* __restrict__ ws) {
  int bx = blockIdx.x, tid = threadIdx.x;
  if (bx < 64) {
    int b = bx >> 2, x = bx & 3;
    int t = x * 256 + tid;
    float s = 0.f;
#pragma unroll 8
    for (int c = 0; c < 64; ++c) s += eeg[(b * 64 + c) * 1024 + t];
    ws[CA_OFF + b * CA_S + 32 + t] = s * fsp[0] * (1.f / 64.f);
    if (x == 0 && tid < 32) ws[CA_OFF + b * CA_S + tid] = 0.f;
    if (x == 3 && tid >= 224) ws[CA_OFF + b * CA_S + 1056 + (tid - 224)] = 0.f;
    return;
  }
  int id = (bx - 64) * 256 + tid;
  if (id < 16384) {                       // aw2: 65536 elems
    int e0 = id * 4;
    float4 f = *(const float4*)&aw2[e0];
    unsigned short* d = (unsigned short*)ws + WAW2_U + e0;
    d[0] = f2bf(f.x); d[1] = f2bf(f.y); d[2] = f2bf(f.z); d[3] = f2bf(f.w);
  } else if (id < 32768) {                // fw2: 65536 elems
    int e0 = (id - 16384) * 4;
    float4 f = *(const float4*)&fw2[e0];
    unsigned short* d = (unsigned short*)ws + WFW2_U + e0;
    d[0] = f2bf(f.x); d[1] = f2bf(f.y); d[2] = f2bf(f.z); d[3] = f2bf(f.w);
  } else if (id < 34816) {                // fw1: 8192 elems
    int e0 = (id - 32768) * 4;
    float4 f = *(const float4*)&fw1[e0];
    unsigned short* d = (unsigned short*)ws + WFW1_U + e0;
    d[0] = f2bf(f.x); d[1] = f2bf(f.y); d[2] = f2bf(f.z); d[3] = f2bf(f.w);
  }
}

// K2s: per (b,o) row: a1 = relu(conv1d(ca, aw1, pad=32)) computed in LDS,
// then write 4 shifted bf16 copies directly. 512 blocks.
__global__ void k2s_conv1(const float* __restrict__ aw1, const float* __restrict__ ab1,
                          float* __restrict__ ws) {
  int row = blockIdx.x;            // b*32 + o
  int b = row >> 5, o = row & 31;
  int tid = threadIdx.x;
  __shared__ unsigned short xl[1232];
  for (int i = tid; i < 1232; i += 256)
    if (i < 16 || i >= 1041) xl[i] = 0;
  const float* cab = ws + CA_OFF + b * CA_S;
  float bias = ab1[o];
  for (int t = tid; t < 1025; t += 256) {
    float acc = bias;
#pragma unroll 8
    for (int k = 0; k < 64; ++k) acc += aw1[o * 64 + k] * cab[t + k];
    xl[16 + t] = f2bf(fmaxf(acc, 0.f));
  }
  __syncthreads();
  unsigned short* a1s = (unsigned short*)ws + A1S_U;
  for (int q = tid; q < 608; q += 256) {
    int s = q / 152, mm = q % 152;
    int e = mm * 8;
    unsigned a0 = xl[e + s + 0], a1 = xl[e + s + 1], a2 = xl[e + s + 2], a3 = xl[e + s + 3];
    unsigned a4 = xl[e + s + 4], a5 = xl[e + s + 5], a6 = xl[e + s + 6], a7 = xl[e + s + 7];
    uint4 v;
    v.x = a0 | (a1 << 16); v.y = a2 | (a3 << 16); v.z = a4 | (a5 << 16); v.w = a6 | (a7 << 16);
    *(uint4*)&a1s[(s * 512 + row) * 1216 + e] = v;
  }
}

// K3: MFMA conv2 (R6 version: weight tile in LDS). grid(17, B, 4). Writes a2 fp32.
__global__ __launch_bounds__(256) void k3_mfma(const float* __restrict__ ab2,
                                               float* __restrict__ ws) {
  int t0 = blockIdx.x * 64, b = blockIdx.y, oh = blockIdx.z;
  int tid = threadIdx.x, l = tid & 63, w = tid >> 6;
  __shared__ unsigned short wlds[16 * 1032];
  __shared__ unsigned short xlds[32 * 4 * 104];
  const unsigned short* wb = (const unsigned short*)ws + WAW2_U;
  const unsigned short* a1s = (const unsigned short*)ws + A1S_U;
#pragma unroll
  for (int r = 0; r < 8; ++r) {
    int idx = tid + r * 256;
    int o = idx >> 7, j = idx & 127;
    *(uint4*)&wlds[o * 1032 + j * 8] = *(const uint4*)&wb[(oh * 16 + o) * 1024 + j * 8];
  }
#pragma unroll
  for (int r = 0; r < 6; ++r) {
    int idx = tid + r * 256;
    int i = idx / 48, rem = idx % 48, s = rem / 12, mm = rem % 12;
    *(uint4*)&xlds[(i * 4 + s) * 104 + mm * 8] =
        *(const uint4*)&a1s[(s * 512 + b * 32 + i) * 1216 + t0 + mm * 8];
  }
  __syncthreads();
  int m = l & 15, q = l >> 4;
  int A0 = w * 16 + m + q * 8;
  int xoffb = (A0 & 3) * 104 + (A0 & ~3);
  f32x4 acc = (f32x4){0.f, 0.f, 0.f, 0.f};
  for (int i = 0; i < 32; ++i) {
    const uint2* p = (const uint2*)&xlds[i * 416 + xoffb];
    uint2 lo = p[0], hi = p[1];
    u32x4 bb; bb.x = lo.x; bb.y = lo.y; bb.z = hi.x; bb.w = hi.y;
    u32x4 a = *(const u32x4*)&wlds[m * 1032 + i * 32 + q * 8];
    acc = __builtin_amdgcn_mfma_f32_16x16x32_bf16(
        __builtin_bit_cast(bf16x8, a), __builtin_bit_cast(bf16x8, bb), acc, 0, 0, 0);
  }
  int t = t0 + w * 16 + m;
  if (t < 1026) {
#pragma unroll
    for (int r = 0; r < 4; ++r) {
      int o = oh * 16 + q * 4 + r;
      ws[A2_OFF + (b * 64 + o) * A2_S + t] = fmaxf(acc[r] + ab2[o], 0.f);
    }
  }
}

// K4: fused pooled 1x1 conv + sigmoid -> attn + out2. 64 blocks.
__global__ void k4_attn(const float* __restrict__ aw3, const float* __restrict__ ab3,
                        float* __restrict__ ws, float* __restrict__ out) {
  int b = blockIdx.y, t = blockIdx.x * 256 + threadIdx.x;
  int s = t + (t >= 512 ? 1 : 0);
  float acc = 0.f;
#pragma unroll 8
  for (int i = 0; i < 64; ++i) {
    const float* row = ws + A2_OFF + (b * 64 + i) * A2_S;
    acc += aw3[i] * (row[s] + row[s + 1]);
  }
  float a = 1.f / (1.f + expf(-(acc * 0.5f + ab3[0])));
  ws[AT_OFF + b * 1024 + t] = a;
  out[16777216 + b * 1024 + t] = a;
}

// K4b: build 4 shifted bf16 copies of xs_pad = pad64(eeg*fs*attn), row len 1280
__global__ void k4b_xs(const float* __restrict__ eeg, const float* __restrict__ fsp,
                       float* __restrict__ ws) {
  int bc = blockIdx.x;
  int b = bc >> 6;
  int tid = threadIdx.x;
  __shared__ unsigned short xsl[1288];
  float fs = fsp[0];
  for (int i = tid; i < 1288; i += 256) {
    int j = i - 64;
    float v = 0.f;
    if (j >= 0 && j < 1024) v = eeg[bc * 1024 + j] * fs * ws[AT_OFF + b * 1024 + j];
    xsl[i] = f2bf(v);
  }
  __syncthreads();
  unsigned short* xsg = (unsigned short*)ws + XS_U;
  for (int q = tid; q < 640; q += 256) {
    int s = q / 160, m = q % 160, e = m * 8;
    uint4 v;
    unsigned a0 = xsl[e + s + 0], a1 = xsl[e + s + 1], a2 = xsl[e + s + 2], a3 = xsl[e + s + 3];
    unsigned a4 = xsl[e + s + 4], a5 = xsl[e + s + 5], a6 = xsl[e + s + 6], a7 = xsl[e + s + 7];
    v.x = a0 | (a1 << 16); v.y = a2 | (a3 << 16); v.z = a4 | (a5 << 16); v.w = a6 | (a7 << 16);
    *(uint4*)&xsg[(s * 1024 + bc) * 1280 + e] = v;
  }
}

// K5: MFMA stage-B conv. Weight frags hoisted from global (L2-hot, loop-invariant);
// LDS = xlds only (51.2KB) -> 3 blocks/CU. Writes bf16 HSB = Hsum/128.
__global__ __launch_bounds__(256, 3) void k5_mfma(
    const float* __restrict__ fb1,
    const float* __restrict__ bng, const float* __restrict__ bnb,
    const float* __restrict__ bnm, const float* __restrict__ bnv,
    float* __restrict__ ws) {
  int t0 = blockIdx.x * 64, b = blockIdx.y, g2 = blockIdx.z;
  int tid = threadIdx.x, l = tid & 63, w = tid >> 6;
  __shared__ unsigned short xlds[32 * 4 * 200];
  const unsigned short* wbf = (const unsigned short*)ws + WFW1_U;
  const unsigned short* xsg = (const unsigned short*)ws + XS_U;
#pragma unroll
  for (int r = 0; r < 12; ++r) {
    int q = tid + r * 256;
    int ch = q / 96, rem = q % 96, s = rem / 24, m = rem % 24;
    int c = g2 * 32 + ch;
    uint4 v = *(const uint4*)&xsg[((s * 1024) + b * 64 + c) * 1280 + t0 + m * 8];
    *(uint4*)&xlds[(ch * 4 + s) * 200 + m * 8] = v;
  }
  u32x4 wf[4][4];
#pragma unroll
  for (int mt = 0; mt < 4; ++mt)
#pragma unroll
    for (int ks = 0; ks < 4; ++ks)
      wf[mt][ks] = *(const u32x4*)&wbf[(mt * 16 + (l & 15)) * 128 + ks * 32 + (l >> 4) * 8];
  int row0 = (l >> 4) * 4;
  float scv[4][4], shv[4][4];
#pragma unroll
  for (int mt = 0; mt < 4; ++mt)
#pragma unroll
    for (int r = 0; r < 4; ++r) {
      int o = mt * 16 + row0 + r;
      float s = bng[o] * rsqrtf(bnv[o] + 1e-5f);
      scv[mt][r] = s;
      shv[mt][r] = (fb1[o] - bnm[o]) * s + bnb[o];
    }
  int xoff[4];
#pragma unroll
  for (int ks = 0; ks < 4; ++ks) {
    int A0 = (l & 15) + ks * 32 + (l >> 4) * 8;
    int s = A0 & 3, e = A0 & ~3;
    xoff[ks] = s * 200 + w * 16 + e;
  }
  __syncthreads();
  f32x4 acc[4];
#pragma unroll
  for (int mt = 0; mt < 4; ++mt) acc[mt] = (f32x4){0.f, 0.f, 0.f, 0.f};
  for (int ch = 0; ch < 32; ++ch) {
    u32x4 bf[4];
#pragma unroll
    for (int ks = 0; ks < 4; ++ks) {
      const uint2* p = (const uint2*)&xlds[ch * 800 + xoff[ks]];
      uint2 lo = p[0], hi = p[1];
      u32x4 bb; bb.x = lo.x; bb.y = lo.y; bb.z = hi.x; bb.w = hi.y;
      bf[ks] = bb;
    }
#pragma unroll
    for (int mt = 0; mt < 4; ++mt) {
      f32x4 c = (f32x4){0.f, 0.f, 0.f, 0.f};
#pragma unroll
      for (int ks = 0; ks < 4; ++ks)
        c = __builtin_amdgcn_mfma_f32_16x16x32_bf16(
            __builtin_bit_cast(bf16x8, wf[mt][ks]),
            __builtin_bit_cast(bf16x8, bf[ks]), c, 0, 0, 0);
#pragma unroll
      for (int r = 0; r < 4; ++r)
        acc[mt][r] += fmaxf(c[r] * scv[mt][r] + shv[mt][r], 0.f);
    }
  }
  int t = t0 + w * 16 + (l & 15);
  unsigned short* hsb = (unsigned short*)ws + HSB_U;
  if (t < 1025) {
#pragma unroll
    for (int mt = 0; mt < 4; ++mt)
#pragma unroll
      for (int r = 0; r < 4; ++r)
        hsb[(((g2 * 16 + b) * 64) + mt * 16 + row0 + r) * 1040 + t] =
            f2bf(acc[mt][r] * 0.0078125f);
  }
}

// K6: MFMA out-GEMM, B-tile staged from HSB with fused 2-tap pool + g-sum.
// 64x64 tile, grid(16 tt, 16 dt, 16 b). out[b][d][t] = sum_k fw2[d][k]*hbar[k][t] + fb2[d]
__global__ __launch_bounds__(256) void k6_mfma(const float* __restrict__ fb2,
                                               float* __restrict__ ws,
                                               float* __restrict__ out) {
  int tt = blockIdx.x, dt = blockIdx.y, b = blockIdx.z;
  int tid = threadIdx.x, l = tid & 63, w = tid >> 6;
  int wd = w >> 1, wt = w & 1;
  __shared__ unsigned short wA[64 * 80], xB[64 * 80];
  const unsigned short* w2 = (const unsigned short*)ws + WFW2_U;
  const unsigned short* hsb = (const unsigned short*)ws + HSB_U;
#pragma unroll
  for (int r = 0; r < 2; ++r) {
    int idx = tid + r * 256;
    int row = idx >> 3, j = idx & 7;
    *(uint4*)&wA[row * 80 + j * 8] = *(const uint4*)&w2[(dt * 64 + row) * 64 + j * 8];
  }
  {
    int k = tid >> 2, q = tid & 3;
    const unsigned short* h0 = hsb + ((0 + b) * 64 + k) * 1040 + tt * 64 + q * 16;
    const unsigned short* h1 = hsb + ((16 + b) * 64 + k) * 1040 + tt * 64 + q * 16;
#pragma unroll
    for (int j = 0; j < 16; ++j) {
      float v = bf2f(h0[j]) + bf2f(h0[j + 1]) + bf2f(h1[j]) + bf2f(h1[j + 1]);
      xB[(q * 16 + j) * 80 + k] = f2bf(v);
    }
  }
  __syncthreads();
  int m = l & 15, q = l >> 4;
  f32x4 acc[2][2];
#pragma unroll
  for (int mt = 0; mt < 2; ++mt)
#pragma unroll
    for (int nt = 0; nt < 2; ++nt) acc[mt][nt] = (f32x4){0.f, 0.f, 0.f, 0.f};
#pragma unroll
  for (int ks = 0; ks < 2; ++ks) {
    u32x4 a[2], bb[2];
#pragma unroll
    for (int mt = 0; mt < 2; ++mt)
      a[mt] = *(const u32x4*)&wA[(wd * 32 + mt * 16 + m) * 80 + ks * 32 + q * 8];
#pragma unroll
    for (int nt = 0; nt < 2; ++nt)
      bb[nt] = *(const u32x4*)&xB[(wt * 32 + nt * 16 + m) * 80 + ks * 32 + q * 8];
#pragma unroll
    for (int mt = 0; mt < 2; ++mt)
#pragma unroll
      for (int nt = 0; nt < 2; ++nt)
        acc[mt][nt] = __builtin_amdgcn_mfma_f32_16x16x32_bf16(
            __builtin_bit_cast(bf16x8, a[mt]), __builtin_bit_cast(bf16x8, bb[nt]),
            acc[mt][nt], 0, 0, 0);
  }
#pragma unroll
  for (int mt = 0; mt < 2; ++mt) {
#pragma unroll
    for (int r = 0; r < 4; ++r) {
      int d = dt * 64 + wd * 32 + mt * 16 + q * 4 + r;
      float bias = fb2[d];
#pragma unroll
      for (int nt = 0; nt < 2; ++nt) {
        int t = tt * 64 + wt * 32 + nt * 16 + m;
        out[(b * 1024 + d) * 1024 + t] = acc[mt][nt][r] + bias;
      }
    }
  }
}

extern "C" void kernel_launch(void* const* d_in, const int* in_sizes, int n_in,
                              void* d_out, int out_size, void* d_ws, size_t ws_size,
                              hipStream_t stream) {
  const float* eeg = (const float*)d_in[0];
  const float* fsp = (const float*)d_in[1];
  const float* aw1 = (const float*)d_in[2];
  const float* ab1 = (const float*)d_in[3];
  const float* aw2 = (const float*)d_in[4];
  const float* ab2 = (const float*)d_in[5];
  const float* aw3 = (const float*)d_in[6];
  const float* ab3 = (const float*)d_in[7];
  const float* fw1 = (const float*)d_in[8];
  const float* fb1 = (const float*)d_in[9];
  const float* bng = (const float*)d_in[10];
  const float* bnb = (const float*)d_in[11];
  const float* bnm = (const float*)d_in[12];
  const float* bnv = (const float*)d_in[13];
  const float* fw2 = (const float*)d_in[14];
  const float* fb2 = (const float*)d_in[15];
  float* out = (float*)d_out;
  float* ws = (float*)d_ws;

  hipLaunchKernelGGL(kI_init, dim3(200), dim3(256), 0, stream, eeg, fsp, aw2, fw2, fw1, ws);
  hipLaunchKernelGGL(k2s_conv1, dim3(512), dim3(256), 0, stream, aw1, ab1, ws);
  hipLaunchKernelGGL(k3_mfma, dim3(17, 16, 4), dim3(256), 0, stream, ab2, ws);
  hipLaunchKernelGGL(k4_attn, dim3(4, 16), dim3(256), 0, stream, aw3, ab3, ws, out);
  hipLaunchKernelGGL(k4b_xs, dim3(1024), dim3(256), 0, stream, eeg, fsp, ws);
  hipLaunchKernelGGL(k5_mfma, dim3(17, 16, 2), dim3(256), 0, stream,
                     fb1, bng, bnb, bnm, bnv, ws);
  hipLaunchKernelGGL(k6_mfma, dim3(16, 16, 16), dim3(256), 0, stream, fb2, ws, out);
}

// Round 10
// 173.784 us; speedup vs baseline: 1.0962x; 1.0428x over previous
//
#include <hip/hip_runtime.h>
#include <math.h>

#define Bn 16
#define Cn 64
#define Tn 1024
#define Dn 1024

// ---- workspace layout (float element offsets) ----
// CAP: fp32 ca partials [4][16][1088] = [0, 69632)  (dead after k2s; k4b's XS
//      write clobbers floats >=50176 -- safe by ordering)
#define CAP_S  1088
#define A2_S   1026
#define A2_OFF 599040                            // fp32 a2 [B*64][1026] (inside XS range; dead before k4b)
#define AT_OFF 3916800                           // attn [B][1024] floats (after A1S/HSB; alive k4->k4b only)

// ---- ushort offsets ----
#define XS_U   (2*50176)                         // bf16 xs [4][B*C][1280] = floats [50176, 2671616)
#define A1S_U  (2*2671616)                       // bf16 a1 shifted [4][512][1216] = floats [2671616, 3916800); dead after k3
#define HSB_U  A1S_U                             // bf16 Hsum/128 [2][B][64][1040] = floats [2671616, 3736256); overlays A1S
#define WFW2_U (2*4801536 + 1048576)             // bf16 fw2 [1024][64]
#define WAW2_U (WFW2_U + 65536)                  // bf16 aw2 [64][32][32]
#define WFW1_U (WAW2_U + 65536)                  // bf16 fw1 [64][128]

typedef __attribute__((ext_vector_type(4))) float f32x4;
typedef __attribute__((ext_vector_type(8))) short bf16x8;
typedef __attribute__((ext_vector_type(4))) unsigned int u32x4;

static __device__ inline unsigned short f2bf(float x) {
  unsigned u = __builtin_bit_cast(unsigned, x);
  return (unsigned short)((u + 0x7fffu + ((u >> 16) & 1u)) >> 16);
}
static __device__ inline float bf2f(unsigned short h) {
  unsigned u = ((unsigned)h) << 16;
  return __builtin_bit_cast(float, u);
}

// KI: blocks 0..255: CAP[cg][b][t] = fs/64 * sum_{16ch} eeg  (4-way split, no atomics)
//     blocks 256..391: convert aw2 / fw2 / fw1 -> bf16
__global__ void kI_init(const float* __restrict__ eeg, const float* __restrict__ fsp,
                        const float* __restrict__ aw2, const float* __restrict__ fw2,
                        const float* __restrict__ fw1, float* __restrict__ ws) {
  int bx = blockIdx.x, tid = threadIdx.x;
  if (bx < 256) {
    int cg = bx >> 6, rem = bx & 63, b = rem >> 2, x = rem & 3;
    int t = x * 256 + tid;
    int c0 = cg * 16;
    float s = 0.f;
#pragma unroll
    for (int j = 0; j < 16; ++j) s += eeg[(b * 64 + c0 + j) * 1024 + t];
    float* cap = ws + cg * 16 * CAP_S + b * CAP_S;
    cap[32 + t] = s * fsp[0] * (1.f / 64.f);
    if (x == 0 && tid < 32) cap[tid] = 0.f;
    if (x == 3 && tid >= 224) cap[1056 + (tid - 224)] = 0.f;
    return;
  }
  int id = (bx - 256) * 256 + tid;
  if (id < 16384) {                       // aw2: 65536 elems
    int e0 = id * 4;
    float4 f = *(const float4*)&aw2[e0];
    unsigned short* d = (unsigned short*)ws + WAW2_U + e0;
    d[0] = f2bf(f.x); d[1] = f2bf(f.y); d[2] = f2bf(f.z); d[3] = f2bf(f.w);
  } else if (id < 32768) {                // fw2: 65536 elems
    int e0 = (id - 16384) * 4;
    float4 f = *(const float4*)&fw2[e0];
    unsigned short* d = (unsigned short*)ws + WFW2_U + e0;
    d[0] = f2bf(f.x); d[1] = f2bf(f.y); d[2] = f2bf(f.z); d[3] = f2bf(f.w);
  } else if (id < 34816) {                // fw1: 8192 elems
    int e0 = (id - 32768) * 4;
    float4 f = *(const float4*)&fw1[e0];
    unsigned short* d = (unsigned short*)ws + WFW1_U + e0;
    d[0] = f2bf(f.x); d[1] = f2bf(f.y); d[2] = f2bf(f.z); d[3] = f2bf(f.w);
  }
}

// K2s: per (b,o) row: sum CAP parts into LDS, a1 = relu(conv1d(ca, aw1, pad=32)),
// then write 4 shifted bf16 copies. 512 blocks.
__global__ void k2s_conv1(const float* __restrict__ aw1, const float* __restrict__ ab1,
                          float* __restrict__ ws) {
  int row = blockIdx.x;            // b*32 + o
  int b = row >> 5, o = row & 31;
  int tid = threadIdx.x;
  __shared__ unsigned short xl[1232];
  __shared__ float cal[1092];
  for (int i = tid; i < 1232; i += 256)
    if (i < 16 || i >= 1041) xl[i] = 0;
  {
    const float* c0 = ws + 0 * 16 * CAP_S + b * CAP_S;
    const float* c1 = ws + 1 * 16 * CAP_S + b * CAP_S;
    const float* c2 = ws + 2 * 16 * CAP_S + b * CAP_S;
    const float* c3 = ws + 3 * 16 * CAP_S + b * CAP_S;
    for (int i = tid; i < 1089; i += 256)
      cal[i] = c0[i] + c1[i] + c2[i] + c3[i];
  }
  __syncthreads();
  float bias = ab1[o];
  for (int t = tid; t < 1025; t += 256) {
    float acc = bias;
#pragma unroll 8
    for (int k = 0; k < 64; ++k) acc += aw1[o * 64 + k] * cal[t + k];
    xl[16 + t] = f2bf(fmaxf(acc, 0.f));
  }
  __syncthreads();
  unsigned short* a1s = (unsigned short*)ws + A1S_U;
  for (int q = tid; q < 608; q += 256) {
    int s = q / 152, mm = q % 152;
    int e = mm * 8;
    unsigned a0 = xl[e + s + 0], a1 = xl[e + s + 1], a2 = xl[e + s + 2], a3 = xl[e + s + 3];
    unsigned a4 = xl[e + s + 4], a5 = xl[e + s + 5], a6 = xl[e + s + 6], a7 = xl[e + s + 7];
    uint4 v;
    v.x = a0 | (a1 << 16); v.y = a2 | (a3 << 16); v.z = a4 | (a5 << 16); v.w = a6 | (a7 << 16);
    *(uint4*)&a1s[(s * 512 + row) * 1216 + e] = v;
  }
}

// K3: MFMA conv2 (weight tile in LDS). grid(17, B, 4). Writes a2 fp32.
__global__ __launch_bounds__(256) void k3_mfma(const float* __restrict__ ab2,
                                               float* __restrict__ ws) {
  int t0 = blockIdx.x * 64, b = blockIdx.y, oh = blockIdx.z;
  int tid = threadIdx.x, l = tid & 63, w = tid >> 6;
  __shared__ unsigned short wlds[16 * 1032];
  __shared__ unsigned short xlds[32 * 4 * 104];
  const unsigned short* wb = (const unsigned short*)ws + WAW2_U;
  const unsigned short* a1s = (const unsigned short*)ws + A1S_U;
#pragma unroll
  for (int r = 0; r < 8; ++r) {
    int idx = tid + r * 256;
    int o = idx >> 7, j = idx & 127;
    *(uint4*)&wlds[o * 1032 + j * 8] = *(const uint4*)&wb[(oh * 16 + o) * 1024 + j * 8];
  }
#pragma unroll
  for (int r = 0; r < 6; ++r) {
    int idx = tid + r * 256;
    int i = idx / 48, rem = idx % 48, s = rem / 12, mm = rem % 12;
    *(uint4*)&xlds[(i * 4 + s) * 104 + mm * 8] =
        *(const uint4*)&a1s[(s * 512 + b * 32 + i) * 1216 + t0 + mm * 8];
  }
  __syncthreads();
  int m = l & 15, q = l >> 4;
  int A0 = w * 16 + m + q * 8;
  int xoffb = (A0 & 3) * 104 + (A0 & ~3);
  f32x4 acc = (f32x4){0.f, 0.f, 0.f, 0.f};
  for (int i = 0; i < 32; ++i) {
    const uint2* p = (const uint2*)&xlds[i * 416 + xoffb];
    uint2 lo = p[0], hi = p[1];
    u32x4 bb; bb.x = lo.x; bb.y = lo.y; bb.z = hi.x; bb.w = hi.y;
    u32x4 a = *(const u32x4*)&wlds[m * 1032 + i * 32 + q * 8];
    acc = __builtin_amdgcn_mfma_f32_16x16x32_bf16(
        __builtin_bit_cast(bf16x8, a), __builtin_bit_cast(bf16x8, bb), acc, 0, 0, 0);
  }
  int t = t0 + w * 16 + m;
  if (t < 1026) {
#pragma unroll
    for (int r = 0; r < 4; ++r) {
      int o = oh * 16 + q * 4 + r;
      ws[A2_OFF + (b * 64 + o) * A2_S + t] = fmaxf(acc[r] + ab2[o], 0.f);
    }
  }
}

// K4: fused pooled 1x1 conv + sigmoid -> attn + out2. 64 blocks.
__global__ void k4_attn(const float* __restrict__ aw3, const float* __restrict__ ab3,
                        float* __restrict__ ws, float* __restrict__ out) {
  int b = blockIdx.y, t = blockIdx.x * 256 + threadIdx.x;
  int s = t + (t >= 512 ? 1 : 0);
  float acc = 0.f;
#pragma unroll 8
  for (int i = 0; i < 64; ++i) {
    const float* row = ws + A2_OFF + (b * 64 + i) * A2_S;
    acc += aw3[i] * (row[s] + row[s + 1]);
  }
  float a = 1.f / (1.f + expf(-(acc * 0.5f + ab3[0])));
  ws[AT_OFF + b * 1024 + t] = a;
  out[16777216 + b * 1024 + t] = a;
}

// K4b: build 4 shifted bf16 copies of xs_pad = pad64(eeg*fs*attn), row len 1280
__global__ void k4b_xs(const float* __restrict__ eeg, const float* __restrict__ fsp,
                       float* __restrict__ ws) {
  int bc = blockIdx.x;
  int b = bc >> 6;
  int tid = threadIdx.x;
  __shared__ unsigned short xsl[1288];
  float fs = fsp[0];
  for (int i = tid; i < 1288; i += 256) {
    int j = i - 64;
    float v = 0.f;
    if (j >= 0 && j < 1024) v = eeg[bc * 1024 + j] * fs * ws[AT_OFF + b * 1024 + j];
    xsl[i] = f2bf(v);
  }
  __syncthreads();
  unsigned short* xsg = (unsigned short*)ws + XS_U;
  for (int q = tid; q < 640; q += 256) {
    int s = q / 160, m = q % 160, e = m * 8;
    uint4 v;
    unsigned a0 = xsl[e + s + 0], a1 = xsl[e + s + 1], a2 = xsl[e + s + 2], a3 = xsl[e + s + 3];
    unsigned a4 = xsl[e + s + 4], a5 = xsl[e + s + 5], a6 = xsl[e + s + 6], a7 = xsl[e + s + 7];
    v.x = a0 | (a1 << 16); v.y = a2 | (a3 << 16); v.z = a4 | (a5 << 16); v.w = a6 | (a7 << 16);
    *(uint4*)&xsg[(s * 1024 + bc) * 1280 + e] = v;
  }
}

// K5: MFMA stage-B conv. Weight frags hoisted (loop-invariant, L2-hot);
// LDS = xlds only (51.2KB) -> 3 blocks/CU. Writes bf16 HSB = Hsum/128.
__global__ __launch_bounds__(256, 3) void k5_mfma(
    const float* __restrict__ fb1,
    const float* __restrict__ bng, const float* __restrict__ bnb,
    const float* __restrict__ bnm, const float* __restrict__ bnv,
    float* __restrict__ ws) {
  int t0 = blockIdx.x * 64, b = blockIdx.y, g2 = blockIdx.z;
  int tid = threadIdx.x, l = tid & 63, w = tid >> 6;
  __shared__ unsigned short xlds[32 * 4 * 200];
  const unsigned short* wbf = (const unsigned short*)ws + WFW1_U;
  const unsigned short* xsg = (const unsigned short*)ws + XS_U;
#pragma unroll
  for (int r = 0; r < 12; ++r) {
    int q = tid + r * 256;
    int ch = q / 96, rem = q % 96, s = rem / 24, m = rem % 24;
    int c = g2 * 32 + ch;
    uint4 v = *(const uint4*)&xsg[((s * 1024) + b * 64 + c) * 1280 + t0 + m * 8];
    *(uint4*)&xlds[(ch * 4 + s) * 200 + m * 8] = v;
  }
  u32x4 wf[4][4];
#pragma unroll
  for (int mt = 0; mt < 4; ++mt)
#pragma unroll
    for (int ks = 0; ks < 4; ++ks)
      wf[mt][ks] = *(const u32x4*)&wbf[(mt * 16 + (l & 15)) * 128 + ks * 32 + (l >> 4) * 8];
  int row0 = (l >> 4) * 4;
  float scv[4][4], shv[4][4];
#pragma unroll
  for (int mt = 0; mt < 4; ++mt)
#pragma unroll
    for (int r = 0; r < 4; ++r) {
      int o = mt * 16 + row0 + r;
      float s = bng[o] * rsqrtf(bnv[o] + 1e-5f);
      scv[mt][r] = s;
      shv[mt][r] = (fb1[o] - bnm[o]) * s + bnb[o];
    }
  int xoff[4];
#pragma unroll
  for (int ks = 0; ks < 4; ++ks) {
    int A0 = (l & 15) + ks * 32 + (l >> 4) * 8;
    int s = A0 & 3, e = A0 & ~3;
    xoff[ks] = s * 200 + w * 16 + e;
  }
  __syncthreads();
  f32x4 acc[4];
#pragma unroll
  for (int mt = 0; mt < 4; ++mt) acc[mt] = (f32x4){0.f, 0.f, 0.f, 0.f};
  for (int ch = 0; ch < 32; ++ch) {
    u32x4 bf[4];
#pragma unroll
    for (int ks = 0; ks < 4; ++ks) {
      const uint2* p = (const uint2*)&xlds[ch * 800 + xoff[ks]];
      uint2 lo = p[0], hi = p[1];
      u32x4 bb; bb.x = lo.x; bb.y = lo.y; bb.z = hi.x; bb.w = hi.y;
      bf[ks] = bb;
    }
#pragma unroll
    for (int mt = 0; mt < 4; ++mt) {
      f32x4 c = (f32x4){0.f, 0.f, 0.f, 0.f};
#pragma unroll
      for (int ks = 0; ks < 4; ++ks)
        c = __builtin_amdgcn_mfma_f32_16x16x32_bf16(
            __builtin_bit_cast(bf16x8, wf[mt][ks]),
            __builtin_bit_cast(bf16x8, bf[ks]), c, 0, 0, 0);
#pragma unroll
      for (int r = 0; r < 4; ++r)
        acc[mt][r] += fmaxf(c[r] * scv[mt][r] + shv[mt][r], 0.f);
    }
  }
  int t = t0 + w * 16 + (l & 15);
  unsigned short* hsb = (unsigned short*)ws + HSB_U;
  if (t < 1025) {
#pragma unroll
    for (int mt = 0; mt < 4; ++mt)
#pragma unroll
      for (int r = 0; r < 4; ++r)
        hsb[(((g2 * 16 + b) * 64) + mt * 16 + row0 + r) * 1040 + t] =
            f2bf(acc[mt][r] * 0.0078125f);
  }
}

// K6: MFMA out-GEMM, B-tile staged from HSB with fused 2-tap pool + g-sum,
// vectorized (2x uint4 + 1 scalar per row-half). 64x64 tile, grid(16,16,16).
__global__ __launch_bounds__(256) void k6_mfma(const float* __restrict__ fb2,
                                               float* __restrict__ ws,
                                               float* __restrict__ out) {
  int tt = blockIdx.x, dt = blockIdx.y, b = blockIdx.z;
  int tid = threadIdx.x, l = tid & 63, w = tid >> 6;
  int wd = w >> 1, wt = w & 1;
  __shared__ unsigned short wA[64 * 80], xB[64 * 80];
  const unsigned short* w2 = (const unsigned short*)ws + WFW2_U;
  const unsigned short* hsb = (const unsigned short*)ws + HSB_U;
#pragma unroll
  for (int r = 0; r < 2; ++r) {
    int idx = tid + r * 256;
    int row = idx >> 3, j = idx & 7;
    *(uint4*)&wA[row * 80 + j * 8] = *(const uint4*)&w2[(dt * 64 + row) * 64 + j * 8];
  }
  {
    int k = tid >> 2, q = tid & 3;
    const unsigned short* h0 = hsb + ((0 + b) * 64 + k) * 1040 + tt * 64 + q * 16;
    const unsigned short* h1 = hsb + ((16 + b) * 64 + k) * 1040 + tt * 64 + q * 16;
    unsigned short a0[18] __attribute__((aligned(16)));
    unsigned short a1[18] __attribute__((aligned(16)));
    *(uint4*)&a0[0] = *(const uint4*)&h0[0];
    *(uint4*)&a0[8] = *(const uint4*)&h0[8];
    a0[16] = h0[16];
    *(uint4*)&a1[0] = *(const uint4*)&h1[0];
    *(uint4*)&a1[8] = *(const uint4*)&h1[8];
    a1[16] = h1[16];
#pragma unroll
    for (int j = 0; j < 16; ++j) {
      float v = bf2f(a0[j]) + bf2f(a0[j + 1]) + bf2f(a1[j]) + bf2f(a1[j + 1]);
      xB[(q * 16 + j) * 80 + k] = f2bf(v);
    }
  }
  __syncthreads();
  int m = l & 15, q = l >> 4;
  f32x4 acc[2][2];
#pragma unroll
  for (int mt = 0; mt < 2; ++mt)
#pragma unroll
    for (int nt = 0; nt < 2; ++nt) acc[mt][nt] = (f32x4){0.f, 0.f, 0.f, 0.f};
#pragma unroll
  for (int ks = 0; ks < 2; ++ks) {
    u32x4 a[2], bb[2];
#pragma unroll
    for (int mt = 0; mt < 2; ++mt)
      a[mt] = *(const u32x4*)&wA[(wd * 32 + mt * 16 + m) * 80 + ks * 32 + q * 8];
#pragma unroll
    for (int nt = 0; nt < 2; ++nt)
      bb[nt] = *(const u32x4*)&xB[(wt * 32 + nt * 16 + m) * 80 + ks * 32 + q * 8];
#pragma unroll
    for (int mt = 0; mt < 2; ++mt)
#pragma unroll
      for (int nt = 0; nt < 2; ++nt)
        acc[mt][nt] = __builtin_amdgcn_mfma_f32_16x16x32_bf16(
            __builtin_bit_cast(bf16x8, a[mt]), __builtin_bit_cast(bf16x8, bb[nt]),
            acc[mt][nt], 0, 0, 0);
  }
#pragma unroll
  for (int mt = 0; mt < 2; ++mt) {
#pragma unroll
    for (int r = 0; r < 4; ++r) {
      int d = dt * 64 + wd * 32 + mt * 16 + q * 4 + r;
      float bias = fb2[d];
#pragma unroll
      for (int nt = 0; nt < 2; ++nt) {
        int t = tt * 64 + wt * 32 + nt * 16 + m;
        out[(b * 1024 + d) * 1024 + t] = acc[mt][nt][r] + bias;
      }
    }
  }
}

extern "C" void kernel_launch(void* const* d_in, const int* in_sizes, int n_in,
                              void* d_out, int out_size, void* d_ws, size_t ws_size,
                              hipStream_t stream) {
  const float* eeg = (const float*)d_in[0];
  const float* fsp = (const float*)d_in[1];
  const float* aw1 = (const float*)d_in[2];
  const float* ab1 = (const float*)d_in[3];
  const float* aw2 = (const float*)d_in[4];
  const float* ab2 = (const float*)d_in[5];
  const float* aw3 = (const float*)d_in[6];
  const float* ab3 = (const float*)d_in[7];
  const float* fw1 = (const float*)d_in[8];
  const float* fb1 = (const float*)d_in[9];
  const float* bng = (const float*)d_in[10];
  const float* bnb = (const float*)d_in[11];
  const float* bnm = (const float*)d_in[12];
  const float* bnv = (const float*)d_in[13];
  const float* fw2 = (const float*)d_in[14];
  const float* fb2 = (const float*)d_in[15];
  float* out = (float*)d_out;
  float* ws = (float*)d_ws;

  hipLaunchKernelGGL(kI_init, dim3(392), dim3(256), 0, stream, eeg, fsp, aw2, fw2, fw1, ws);
  hipLaunchKernelGGL(k2s_conv1, dim3(512), dim3(256), 0, stream, aw1, ab1, ws);
  hipLaunchKernelGGL(k3_mfma, dim3(17, 16, 4), dim3(256), 0, stream, ab2, ws);
  hipLaunchKernelGGL(k4_attn, dim3(4, 16), dim3(256), 0, stream, aw3, ab3, ws, out);
  hipLaunchKernelGGL(k4b_xs, dim3(1024), dim3(256), 0, stream, eeg, fsp, ws);
  hipLaunchKernelGGL(k5_mfma, dim3(17, 16, 2), dim3(256), 0, stream,
                     fb1, bng, bnb, bnm, bnv, ws);
  hipLaunchKernelGGL(k6_mfma, dim3(16, 16, 16), dim3(256), 0, stream, fb2, ws, out);
}